// Round 11
// baseline (1573.312 us; speedup 1.0000x reference)
//
#include <hip/hip_runtime.h>
#include <hip/hip_bf16.h>
#include <math.h>

// ---------------------------------------------------------------------------
// GIN edge-attribute decoder.
// Round 10 -> 11: persistent decoder REVERTED (it serialized staging behind
// MFMA in one block; occupancy 44->29%, dur 243->300). New decoder: per-tile
// blocks again + W2 fragments held in REGISTERS (64 VGPR, compile-time
// indexed) instead of LDS -> sB staging deleted, LDS 32->16KB, occupancy up.
// csr_stats inner loop 2-edge unrolled (two independent gathers in flight).
// All [N,128] intermediates remain bf16 (round-10 win kept).
// Decoder trick: concat(x2[s],x2[d],l)@W1 == ya[s]+yb[d]+l*wl.
// ---------------------------------------------------------------------------

typedef __attribute__((ext_vector_type(8))) __bf16 bf16x8;
typedef __attribute__((ext_vector_type(4))) float f32x4;

__device__ __forceinline__ unsigned int pack_bf16(float a, float b) {
    unsigned short ua = __builtin_bit_cast(unsigned short, __float2bfloat16(a));
    unsigned short ub = __builtin_bit_cast(unsigned short, __float2bfloat16(b));
    return (unsigned int)ua | ((unsigned int)ub << 16);
}
__device__ __forceinline__ float bflo(unsigned int u) {
    return __builtin_bit_cast(float, u << 16);
}
__device__ __forceinline__ float bfhi(unsigned int u) {
    return __builtin_bit_cast(float, u & 0xffff0000u);
}
__device__ __forceinline__ unsigned short bf16r(float a) {
    return __builtin_bit_cast(unsigned short, __float2bfloat16(a));
}

// ---------------- CSR build ----------------

__global__ void hist_dst(const int* __restrict__ edst, int* __restrict__ cursor, int E) {
    int e = blockIdx.x * 256 + threadIdx.x;
    if (e < E) atomicAdd(&cursor[edst[e]], 1);
}

__global__ __launch_bounds__(1024) void scan_deg(const int* deg, int* rowoff, int* cursor, int N) {
    __shared__ int sums[1024];
    const int t = threadIdx.x;
    const int chunk = (N + 1023) >> 10;
    int lo = t * chunk, hi = lo + chunk;
    if (lo > N) lo = N;
    if (hi > N) hi = N;
    int s = 0;
    for (int i = lo; i < hi; ++i) s += deg[i];
    sums[t] = s;
    __syncthreads();
    for (int off = 1; off < 1024; off <<= 1) {
        int add = (t >= off) ? sums[t - off] : 0;
        __syncthreads();
        sums[t] += add;
        __syncthreads();
    }
    int run = sums[t] - s;
    for (int i = lo; i < hi; ++i) {
        int d = deg[i];
        rowoff[i] = run;
        cursor[i] = run;
        run += d;
    }
    if (t == 1023) rowoff[N] = sums[1023];
}

__global__ void fill_csr(const int* __restrict__ esrc, const int* __restrict__ edst,
                         const float* __restrict__ coords,
                         int* cursor, int* __restrict__ perm, int* __restrict__ dperm,
                         int* __restrict__ eperm, float* __restrict__ lperm, int E) {
    int e = blockIdx.x * 256 + threadIdx.x;
    if (e >= E) return;
    int s0 = esrc[e], d0 = edst[e];
    int pos = atomicAdd(&cursor[d0], 1);
    perm[pos] = s0;
    dperm[pos] = d0;
    eperm[pos] = e;
    float dx = coords[d0*3+0] - coords[s0*3+0];
    float dy = coords[d0*3+1] - coords[s0*3+1];
    float dz = coords[d0*3+2] - coords[s0*3+2];
    lperm[pos] = sqrtf(dx*dx + dy*dy + dz*dz);
}

// ---------------- gathers ----------------

__global__ void gather_coords(const float* __restrict__ coords,
                              const int* __restrict__ rowoff, const int* __restrict__ perm,
                              float* __restrict__ agg0, int N) {
    int i = blockIdx.x * 256 + threadIdx.x;
    if (i >= N) return;
    float ax = 0.f, ay = 0.f, az = 0.f;
    int b = rowoff[i], t = rowoff[i+1];
    for (int j = b; j < t; ++j) {
        int p = perm[j];
        ax += coords[p*3+0];
        ay += coords[p*3+1];
        az += coords[p*3+2];
    }
    agg0[i*3+0] = ax; agg0[i*3+1] = ay; agg0[i*3+2] = az;
}

// y[i] = (1+eps)*bnrelu(x[i]) + sum_j bnrelu(x[perm[j]]); x,y bf16; BN from raw stats
__global__ __launch_bounds__(256) void gather_combine_bn(const unsigned short* __restrict__ x,
                                                         const int* __restrict__ rowoff,
                                                         const int* __restrict__ perm,
                                                         const float* __restrict__ st,
                                                         const float* __restrict__ g,
                                                         const float* __restrict__ be,
                                                         float invN,
                                                         const float* __restrict__ eps,
                                                         unsigned short* __restrict__ y, int N) {
    int node = blockIdx.x * 4 + (threadIdx.x >> 6);
    int lane = threadIdx.x & 63;
    if (node >= N) return;
    float ep = 1.f + *eps;
    int c0 = lane*2, c1 = c0 + 1;
    float m0 = st[c0]*invN, m1 = st[c1]*invN;
    float v0 = fmaxf(st[128+c0]*invN - m0*m0, 0.f);
    float v1 = fmaxf(st[128+c1]*invN - m1*m1, 0.f);
    float a0 = g[c0]*rsqrtf(v0 + 1e-5f), a1 = g[c1]*rsqrtf(v1 + 1e-5f);
    float sx = a0, sy = a1;
    float hx = be[c0] - m0*a0, hy = be[c1] - m1*a1;
    const unsigned int* x2 = (const unsigned int*)x;
    int b = rowoff[node], t = rowoff[node+1];
    float accx = 0.f, accy = 0.f;
    int j = b;
    for (; j + 2 <= t; j += 2) {
        unsigned int u0 = x2[(size_t)perm[j]*64 + lane];
        unsigned int u1 = x2[(size_t)perm[j+1]*64 + lane];
        accx += fmaxf(fmaf(bflo(u0), sx, hx), 0.f) + fmaxf(fmaf(bflo(u1), sx, hx), 0.f);
        accy += fmaxf(fmaf(bfhi(u0), sy, hy), 0.f) + fmaxf(fmaf(bfhi(u1), sy, hy), 0.f);
    }
    if (j < t) {
        unsigned int u = x2[(size_t)perm[j]*64 + lane];
        accx += fmaxf(fmaf(bflo(u), sx, hx), 0.f);
        accy += fmaxf(fmaf(bfhi(u), sy, hy), 0.f);
    }
    unsigned int uo = x2[(size_t)node*64 + lane];
    accx = fmaf(ep, fmaxf(fmaf(bflo(uo), sx, hx), 0.f), accx);
    accy = fmaf(ep, fmaxf(fmaf(bfhi(uo), sy, hy), 0.f), accy);
    ((unsigned int*)y)[(size_t)node*64 + lane] = pack_bf16(accx, accy);
}

// ---------------- small kernels ----------------

__global__ __launch_bounds__(256) void lin0(const float* __restrict__ coords,
                                            const float* __restrict__ agg0,
                                            const float* __restrict__ W1,
                                            const float* __restrict__ b1,
                                            const float* __restrict__ eps0,
                                            unsigned short* __restrict__ t1,
                                            float* __restrict__ stats, int nrows) {
    int col = threadIdx.x & 127, half = threadIdx.x >> 7;
    float w0 = W1[col], w1 = W1[128+col], w2 = W1[256+col], bb = b1[col];
    float ep = 1.f + *eps0;
    float s = 0.f, q = 0.f;
    int r0 = blockIdx.x * 64;
    for (int i = 0; i < 32; ++i) {
        int row = r0 + half + 2*i;
        if (row < nrows) {
            float h0 = fmaf(ep, coords[row*3+0], agg0[row*3+0]);
            float h1 = fmaf(ep, coords[row*3+1], agg0[row*3+1]);
            float h2 = fmaf(ep, coords[row*3+2], agg0[row*3+2]);
            float v = fmaf(h0, w0, fmaf(h1, w1, fmaf(h2, w2, bb)));
            t1[row*128+col] = bf16r(v);
            s += v; q += v*v;
        }
    }
    __shared__ float red[512];
    red[half*128+col] = s;
    red[256 + half*128+col] = q;
    __syncthreads();
    if (threadIdx.x < 128) {
        atomicAdd(&stats[col],       red[col] + red[128+col]);
        atomicAdd(&stats[128+col],   red[256+col] + red[384+col]);
    }
}

// W2 [128][64] f32 -> w2t [64 cols][128 k] bf16 (decoder)
__global__ void prep_w2(const float* __restrict__ W2, unsigned short* __restrict__ w2t) {
    int i = blockIdx.x * 256 + threadIdx.x;
    if (i >= 128*64) return;
    int k = i >> 6, c = i & 63;
    w2t[c*128 + k] = bf16r(W2[i]);
}

// 7 node-GEMM weights [128][128] f32 -> [col][k] bf16
__global__ void prep_wT(const float* __restrict__ w0, const float* __restrict__ w1,
                        const float* __restrict__ w2, const float* __restrict__ w3,
                        const float* __restrict__ w4, const float* __restrict__ w5,
                        const float* __restrict__ w6, unsigned short* __restrict__ dst) {
    int m = blockIdx.y;
    const float* src = (m==0)?w0:(m==1)?w1:(m==2)?w2:(m==3)?w3:(m==4)?w4:(m==5)?w5:w6;
    int i = blockIdx.x * 256 + threadIdx.x;
    int k = i >> 7, c = i & 127;
    dst[m*16384 + c*128 + k] = bf16r(src[i]);
}

// ---------------- bf16 MFMA node GEMM: bf16 [N,128] @ [128,128] -> bf16 -----
template<bool IN_BN, bool STATS>
__global__ __launch_bounds__(256) void gemm_mfma(const unsigned short* __restrict__ A,
                                                 const unsigned short* __restrict__ wT,
                                                 const float* __restrict__ bias,
                                                 const float* __restrict__ inst,
                                                 const float* __restrict__ bng,
                                                 const float* __restrict__ bnb,
                                                 float invCnt,
                                                 unsigned short* __restrict__ Cb,
                                                 float* __restrict__ stats, int nrows) {
    __shared__ int4 sAi[1024];           // 16KB
    __shared__ int4 sBi[2048];           // 32KB
    __shared__ float sred[2][4][128];    // 4KB (sc/sh during staging)
    char* sA = (char*)sAi;
    char* sB = (char*)sBi;
    float* sSC = &sred[0][0][0];
    float* sSH = &sred[0][1][0];
    const int tid = threadIdx.x;
    const int tile0 = blockIdx.x * 64;

    if (IN_BN) {
        if (tid < 128) {
            float m = inst[tid] * invCnt;
            float v = fmaxf(inst[128+tid] * invCnt - m*m, 0.f);
            float a = bng[tid] * rsqrtf(v + 1e-5f);
            sSC[tid] = a;
            sSH[tid] = bnb[tid] - m*a;
        }
        __syncthreads();
    }

    // stage sB: wT [128 col][128 k] bf16 -> swizzled
    {
        const int4* src = (const int4*)wT;
        #pragma unroll
        for (int ii = 0; ii < 8; ++ii) {
            int s = tid + 256*ii;
            int col = s >> 4, k16 = s & 15;
            int byte = ((col << 8) + (k16 << 4)) ^ ((col & 7) << 4);
            *(int4*)(sB + byte) = src[s];
        }
    }
    // stage sA: bf16 rows (+optional BN/ReLU) -> swizzled. 1024 slots of 8 bf16.
    {
        const int4* A4 = (const int4*)A;   // 16 slots per row
        #pragma unroll
        for (int ii = 0; ii < 4; ++ii) {
            int s = tid + 256*ii;
            int r = s >> 4, k16 = s & 15;
            int row = tile0 + r;
            int4 raw = make_int4(0,0,0,0);
            if (row < nrows) raw = A4[(size_t)row*16 + k16];
            if (IN_BN) {
                float4 sa = ((const float4*)sSC)[k16*2];
                float4 sb = ((const float4*)sSC)[k16*2+1];
                float4 ha = ((const float4*)sSH)[k16*2];
                float4 hb = ((const float4*)sSH)[k16*2+1];
                unsigned int ux = raw.x, uy = raw.y, uz = raw.z, uw = raw.w;
                float e0 = fmaxf(fmaf(bflo(ux), sa.x, ha.x), 0.f);
                float e1 = fmaxf(fmaf(bfhi(ux), sa.y, ha.y), 0.f);
                float e2 = fmaxf(fmaf(bflo(uy), sa.z, ha.z), 0.f);
                float e3 = fmaxf(fmaf(bfhi(uy), sa.w, ha.w), 0.f);
                float e4 = fmaxf(fmaf(bflo(uz), sb.x, hb.x), 0.f);
                float e5 = fmaxf(fmaf(bfhi(uz), sb.y, hb.y), 0.f);
                float e6 = fmaxf(fmaf(bflo(uw), sb.z, hb.z), 0.f);
                float e7 = fmaxf(fmaf(bfhi(uw), sb.w, hb.w), 0.f);
                raw.x = (int)pack_bf16(e0, e1);
                raw.y = (int)pack_bf16(e2, e3);
                raw.z = (int)pack_bf16(e4, e5);
                raw.w = (int)pack_bf16(e6, e7);
            }
            int byte = ((r << 8) + (k16 << 4)) ^ ((r & 7) << 4);
            *(int4*)(sA + byte) = raw;
        }
    }
    __syncthreads();

    const int l = tid & 63;
    const int w = tid >> 6;
    const int arow = (w << 4) + (l & 15);
    const int kbase = (l >> 4) << 3;
    f32x4 accv[8];
    #pragma unroll
    for (int c = 0; c < 8; ++c) accv[c] = (f32x4){0.f, 0.f, 0.f, 0.f};

    #pragma unroll
    for (int t = 0; t < 4; ++t) {
        int k0 = t*32 + kbase;
        int abyte = ((arow << 8) + (k0 << 1)) ^ ((arow & 7) << 4);
        bf16x8 af = __builtin_bit_cast(bf16x8, *(const int4*)(sA + abyte));
        #pragma unroll
        for (int c = 0; c < 8; ++c) {
            int bcol = (c << 4) + (l & 15);
            int bbyte = ((bcol << 8) + (k0 << 1)) ^ ((bcol & 7) << 4);
            bf16x8 bf = __builtin_bit_cast(bf16x8, *(const int4*)(sB + bbyte));
            accv[c] = __builtin_amdgcn_mfma_f32_16x16x32_bf16(af, bf, accv[c], 0, 0, 0);
        }
    }

    const int rj = (l >> 4) << 2;
    float lsum[8], lsq[8];
    #pragma unroll
    for (int c = 0; c < 8; ++c) {
        int col = (c << 4) + (l & 15);
        float bv = bias ? bias[col] : 0.f;
        f32x4 a = accv[c];
        float s = 0.f, q = 0.f;
        #pragma unroll
        for (int j = 0; j < 4; ++j) {
            int row = tile0 + (w << 4) + rj + j;
            float o = a[j] + bv;
            if (row < nrows) {
                Cb[(size_t)row*128 + col] = bf16r(o);
                if (STATS) { s += o; q += o*o; }
            }
        }
        lsum[c] = s; lsq[c] = q;
    }
    if (STATS) {
        #pragma unroll
        for (int c = 0; c < 8; ++c) {
            lsum[c] += __shfl_xor(lsum[c], 16, 64);
            lsum[c] += __shfl_xor(lsum[c], 32, 64);
            lsq[c]  += __shfl_xor(lsq[c], 16, 64);
            lsq[c]  += __shfl_xor(lsq[c], 32, 64);
        }
        __syncthreads();
        if ((l >> 4) == 0) {
            #pragma unroll
            for (int c = 0; c < 8; ++c) {
                int col = (c << 4) + l;
                sred[0][w][col] = lsum[c];
                sred[1][w][col] = lsq[c];
            }
        }
        __syncthreads();
        if (tid < 128) {
            float s = sred[0][0][tid] + sred[0][1][tid] + sred[0][2][tid] + sred[0][3][tid];
            float q = sred[1][0][tid] + sred[1][1][tid] + sred[1][2][tid] + sred[1][3][tid];
            atomicAdd(&stats[tid], s);
            atomicAdd(&stats[128 + tid], q);
        }
    }
}

// -------- decoder BN stats (bf16 ya/yb), 2-edge unrolled gather -------------
__global__ __launch_bounds__(256) void csr_stats(const unsigned short* __restrict__ ya,
                                                 const unsigned short* __restrict__ yb,
                                                 const int* __restrict__ rowoff,
                                                 const int* __restrict__ perm,
                                                 const float* __restrict__ lperm,
                                                 const float* __restrict__ wl,
                                                 const float* __restrict__ b1,
                                                 float* __restrict__ stats, int N, int nspan) {
    int w = blockIdx.x * 4 + (threadIdx.x >> 6);
    int lane = threadIdx.x & 63;
    const unsigned int* ya2 = (const unsigned int*)ya;
    const unsigned int* yb2 = (const unsigned int*)yb;
    float2 wl2 = ((const float2*)wl)[lane];
    float2 b12 = ((const float2*)b1)[lane];
    float2 s = make_float2(0.f, 0.f), q = make_float2(0.f, 0.f);
    int i0 = w * nspan;
    int i1 = i0 + nspan; if (i1 > N) i1 = N;
    for (int i = i0; i < i1; ++i) {
        unsigned int ub = yb2[(size_t)i*64 + lane];
        float ybx = bflo(ub), yby = bfhi(ub);
        int b = rowoff[i], t = rowoff[i+1];
        int j = b;
        for (; j + 2 <= t; j += 2) {
            int p0 = perm[j], p1 = perm[j+1];
            float l0 = lperm[j], l1 = lperm[j+1];
            unsigned int ua0 = ya2[(size_t)p0*64 + lane];
            unsigned int ua1 = ya2[(size_t)p1*64 + lane];
            float z0x = bflo(ua0) + ybx + fmaf(l0, wl2.x, b12.x);
            float z0y = bfhi(ua0) + yby + fmaf(l0, wl2.y, b12.y);
            float z1x = bflo(ua1) + ybx + fmaf(l1, wl2.x, b12.x);
            float z1y = bfhi(ua1) + yby + fmaf(l1, wl2.y, b12.y);
            s.x += z0x + z1x; s.y += z0y + z1y;
            q.x += fmaf(z0x, z0x, z1x*z1x);
            q.y += fmaf(z0y, z0y, z1y*z1y);
        }
        if (j < t) {
            int p = perm[j];
            float lv = lperm[j];
            unsigned int ua = ya2[(size_t)p*64 + lane];
            float zx = bflo(ua) + ybx + fmaf(lv, wl2.x, b12.x);
            float zy = bfhi(ua) + yby + fmaf(lv, wl2.y, b12.y);
            s.x += zx; s.y += zy;
            q.x += zx*zx; q.y += zy*zy;
        }
    }
    __shared__ float red[1024];
    int wv = threadIdx.x >> 6;
    red[wv*128 + lane*2]       = s.x;
    red[wv*128 + lane*2 + 1]   = s.y;
    red[512 + wv*128 + lane*2]     = q.x;
    red[512 + wv*128 + lane*2 + 1] = q.y;
    __syncthreads();
    if (threadIdx.x < 128) {
        int c = threadIdx.x;
        float ss = red[c] + red[128+c] + red[256+c] + red[384+c];
        float qq = red[512+c] + red[640+c] + red[768+c] + red[896+c];
        atomicAdd(&stats[c], ss);
        atomicAdd(&stats[128+c], qq);
    }
}

// -------- fused decoder (per-tile blocks), W2 fragments in REGISTERS --------
// LDS: sA only (16KB). Each lane preloads its 16 B-fragments (16x16B = 64
// VGPR) straight from w2t (L2-resident, 16KB total).
__global__ __launch_bounds__(256) void decoder_fused(const unsigned short* __restrict__ ya,
                                                     const unsigned short* __restrict__ yb,
                                                     const float* __restrict__ lperm,
                                                     const int* __restrict__ perm,
                                                     const int* __restrict__ dperm,
                                                     const int* __restrict__ eperm,
                                                     const float* __restrict__ wl,
                                                     const float* __restrict__ b1,
                                                     const float* __restrict__ st6,
                                                     const float* __restrict__ dg,
                                                     const float* __restrict__ dbe,
                                                     float invE,
                                                     const unsigned short* __restrict__ w2t,
                                                     const float* __restrict__ b2,
                                                     const float* __restrict__ w3,
                                                     const float* __restrict__ b3p,
                                                     float* __restrict__ out, int E) {
    __shared__ int4 sAi[1024];           // 16KB (z tile only)
    char* sA = (char*)sAi;
    const int tid = threadIdx.x;
    const int tile0 = blockIdx.x * 64;
    const int l = tid & 63;
    const int w = tid >> 6;

    // B fragments: breg[t][c] = w2t[(c*16 + l&15)][t*32 + (l>>4)*8 .. +8]
    bf16x8 breg[4][4];
    {
        const int colidx = l & 15;
        const int krow = (l >> 4) << 3;
        #pragma unroll
        for (int t = 0; t < 4; ++t)
            #pragma unroll
            for (int c = 0; c < 4; ++c) {
                int bcol = (c << 4) + colidx;
                int k0 = t*32 + krow;
                breg[t][c] = __builtin_bit_cast(bf16x8,
                    *(const int4*)(w2t + bcol*128 + k0));
            }
    }

    // stage sA: z = bnrelu(ya[s]+yb[d]+l*wl+b1) -> bf16, swizzled
    {
        const int c4 = tid & 31;
        const int rb = tid >> 5;
        float4 wv = ((const float4*)wl)[c4];
        float4 bb = ((const float4*)b1)[c4];
        float4 s4, t4;
        {
            int cb = c4 * 4;
            #pragma unroll
            for (int j = 0; j < 4; ++j) {
                float m = st6[cb+j] * invE;
                float v = fmaxf(st6[128+cb+j] * invE - m*m, 0.f);
                float a = dg[cb+j] * rsqrtf(v + 1e-5f);
                ((float*)&s4)[j] = a;
                ((float*)&t4)[j] = dbe[cb+j] - m*a;
            }
        }
        const uint2* ya2 = (const uint2*)ya;
        const uint2* yb2 = (const uint2*)yb;
        #pragma unroll
        for (int i = 0; i < 8; ++i) {
            int r = rb + 8*i;
            int row = tile0 + r;
            float4 v = make_float4(0.f, 0.f, 0.f, 0.f);
            if (row < E) {
                int s0 = perm[row], d0 = dperm[row];
                float lv = lperm[row];
                uint2 ua = ya2[(size_t)s0*32 + c4];
                uint2 ubv = yb2[(size_t)d0*32 + c4];
                float vax = bflo(ua.x), vay = bfhi(ua.x), vaz = bflo(ua.y), vaw = bfhi(ua.y);
                float vbx = bflo(ubv.x), vby = bfhi(ubv.x), vbz = bflo(ubv.y), vbw = bfhi(ubv.y);
                v.x = fmaxf(fmaf(vax + vbx + fmaf(lv, wv.x, bb.x), s4.x, t4.x), 0.f);
                v.y = fmaxf(fmaf(vay + vby + fmaf(lv, wv.y, bb.y), s4.y, t4.y), 0.f);
                v.z = fmaxf(fmaf(vaz + vbz + fmaf(lv, wv.z, bb.z), s4.z, t4.z), 0.f);
                v.w = fmaxf(fmaf(vaw + vbw + fmaf(lv, wv.w, bb.w), s4.w, t4.w), 0.f);
            }
            uint2 pk;
            pk.x = pack_bf16(v.x, v.y);
            pk.y = pack_bf16(v.z, v.w);
            int byte = ((r << 8) + (c4 << 3)) ^ ((r & 7) << 4);
            *(uint2*)(sA + byte) = pk;
        }
    }
    __syncthreads();

    const int arow = (w << 4) + (l & 15);
    const int kbase = (l >> 4) << 3;
    f32x4 accv[4];
    #pragma unroll
    for (int c = 0; c < 4; ++c) accv[c] = (f32x4){0.f, 0.f, 0.f, 0.f};

    #pragma unroll
    for (int t = 0; t < 4; ++t) {
        int k0 = t*32 + kbase;
        int abyte = ((arow << 8) + (k0 << 1)) ^ ((arow & 7) << 4);
        bf16x8 af = __builtin_bit_cast(bf16x8, *(const int4*)(sA + abyte));
        #pragma unroll
        for (int c = 0; c < 4; ++c) {
            accv[c] = __builtin_amdgcn_mfma_f32_16x16x32_bf16(af, breg[t][c], accv[c], 0, 0, 0);
        }
    }

    float p0 = 0.f, p1 = 0.f, p2 = 0.f, p3 = 0.f;
    #pragma unroll
    for (int c = 0; c < 4; ++c) {
        int col = (c << 4) + (l & 15);
        float b2c = b2[col], w3c = w3[col];
        f32x4 a = accv[c];
        p0 = fmaf(fmaxf(a[0] + b2c, 0.f), w3c, p0);
        p1 = fmaf(fmaxf(a[1] + b2c, 0.f), w3c, p1);
        p2 = fmaf(fmaxf(a[2] + b2c, 0.f), w3c, p2);
        p3 = fmaf(fmaxf(a[3] + b2c, 0.f), w3c, p3);
    }
    #pragma unroll
    for (int m = 1; m < 16; m <<= 1) {
        p0 += __shfl_xor(p0, m, 64);
        p1 += __shfl_xor(p1, m, 64);
        p2 += __shfl_xor(p2, m, 64);
        p3 += __shfl_xor(p3, m, 64);
    }
    if ((l & 15) == 0) {
        float b3v = b3p[0];
        int rbase = tile0 + (w << 4) + ((l >> 4) << 2);
        float pj[4] = {p0, p1, p2, p3};
        #pragma unroll
        for (int j = 0; j < 4; ++j) {
            int row = rbase + j;
            if (row < E) out[eperm[row]] = 1.f / (1.f + expf(-(pj[j] + b3v)));
        }
    }
}

// ---------------------------------------------------------------------------

extern "C" void kernel_launch(void* const* d_in, const int* in_sizes, int n_in,
                              void* d_out, int out_size, void* d_ws, size_t ws_size,
                              hipStream_t stream) {
    const int N = in_sizes[0] / 3;
    const int E = in_sizes[1] / 2;

    const float* coords = (const float*)d_in[0];
    const int*   ei     = (const int*)d_in[1];
    const int*   esrc = ei;
    const int*   edst = ei + E;
    const float* g0_w1 = (const float*)d_in[2];
    const float* g0_b1 = (const float*)d_in[3];
    const float* g0_g1 = (const float*)d_in[4];
    const float* g0_be1= (const float*)d_in[5];
    const float* g0_w2 = (const float*)d_in[6];
    const float* g0_b2 = (const float*)d_in[7];
    const float* g0_g2 = (const float*)d_in[8];
    const float* g0_be2= (const float*)d_in[9];
    const float* g0_w3 = (const float*)d_in[10];
    const float* g0_b3 = (const float*)d_in[11];
    const float* eps0  = (const float*)d_in[12];
    const float* bn0_g = (const float*)d_in[13];
    const float* bn0_b = (const float*)d_in[14];
    const float* g1_w1 = (const float*)d_in[15];
    const float* g1_b1 = (const float*)d_in[16];
    const float* g1_g1 = (const float*)d_in[17];
    const float* g1_be1= (const float*)d_in[18];
    const float* g1_w2 = (const float*)d_in[19];
    const float* g1_b2 = (const float*)d_in[20];
    const float* g1_g2 = (const float*)d_in[21];
    const float* g1_be2= (const float*)d_in[22];
    const float* g1_w3 = (const float*)d_in[23];
    const float* g1_b3 = (const float*)d_in[24];
    const float* eps1  = (const float*)d_in[25];
    const float* bn1_g = (const float*)d_in[26];
    const float* bn1_b = (const float*)d_in[27];
    const float* d_w1  = (const float*)d_in[28];
    const float* d_b1  = (const float*)d_in[29];
    const float* d_g   = (const float*)d_in[30];
    const float* d_be  = (const float*)d_in[31];
    const float* d_w2  = (const float*)d_in[32];
    const float* d_b2  = (const float*)d_in[33];
    const float* d_w3  = (const float*)d_in[34];
    const float* d_b3  = (const float*)d_in[35];

    float* ws = (float*)d_ws;
    const size_t NF = (size_t)N * 128;
    float* buf0 = ws;
    float* buf1 = ws + NF;
    float* buf2 = ws + 2*NF;
    float* agg0 = ws + 3*NF;                 // N*3
    float* stats= agg0 + (size_t)N*3;        // 7*256
    float* scsh = stats + 7*256;             // 7*256 (layout keep)
    float* lperm = scsh + 7*256;             // E
    int*   cursor = (int*)(lperm + E);       // N
    int*   rowoff = cursor + N;              // N+1
    int*   perm   = rowoff + N + 1;          // E
    int*   dperm  = perm + E;                // E
    int*   eperm  = dperm + E;               // E
    unsigned short* w2t = (unsigned short*)(eperm + E);  // 64*128 bf16
    unsigned short* wT  = w2t + 64*128;                  // 7 * 128*128 bf16

    unsigned short* b0 = (unsigned short*)buf0;
    unsigned short* b1b = (unsigned short*)buf1;
    unsigned short* b2b = (unsigned short*)buf2;

    float* out = (float*)d_out;

    const float* wl = d_w1 + 256*128;   // row 256 of d_w1

    #define STATSK(k) (stats + (k)*256)
    #define WT(m) (wT + (m)*16384)

    const int rowTiles = (N + 63) / 64;
    const int edgeTiles = (E + 63) / 64;
    const int eBlocks = (E + 255) / 256;
    const float invN = 1.f / (float)N;
    const float invE = 1.f / (float)E;
    const int nWaves = 2048 * 4;
    const int nspan = (N + nWaves - 1) / nWaves;

    hipMemsetAsync(stats, 0, 7*256 * sizeof(float), stream);
    hipMemsetAsync(cursor, 0, (size_t)N * sizeof(int), stream);

    // CSR build + weight prep
    hist_dst<<<eBlocks, 256, 0, stream>>>(edst, cursor, E);
    scan_deg<<<1, 1024, 0, stream>>>(cursor, rowoff, cursor, N);
    fill_csr<<<eBlocks, 256, 0, stream>>>(esrc, edst, coords, cursor, perm, dperm, eperm, lperm, E);
    prep_w2<<<32, 256, 0, stream>>>(d_w2, w2t);
    prep_wT<<<dim3(64, 7), 256, 0, stream>>>(g0_w2, g0_w3, g1_w1, g1_w2, g1_w3,
                                             d_w1, d_w1 + 128*128, wT);

    // layer 0
    gather_coords<<<(N + 255)/256, 256, 0, stream>>>(coords, rowoff, perm, agg0, N);
    lin0<<<rowTiles, 256, 0, stream>>>(coords, agg0, g0_w1, g0_b1, eps0, b0, STATSK(0), N);
    gemm_mfma<true,true><<<rowTiles, 256, 0, stream>>>(
        b0, WT(0), g0_b2, STATSK(0), g0_g1, g0_be1, invN, b1b, STATSK(1), N);
    gemm_mfma<true,true><<<rowTiles, 256, 0, stream>>>(
        b1b, WT(1), g0_b3, STATSK(1), g0_g2, g0_be2, invN, b2b, STATSK(2), N);

    // layer 1: h1 = (1+eps1)*bnrelu(t3) + gather(bnrelu(t3))
    gather_combine_bn<<<(N + 3)/4, 256, 0, stream>>>(
        b2b, rowoff, perm, STATSK(2), bn0_g, bn0_b, invN, eps1, b0, N);
    gemm_mfma<false,true><<<rowTiles, 256, 0, stream>>>(
        b0, WT(2), g1_b1, nullptr, nullptr, nullptr, 0.f, b1b, STATSK(3), N);
    gemm_mfma<true,true><<<rowTiles, 256, 0, stream>>>(
        b1b, WT(3), g1_b2, STATSK(3), g1_g1, g1_be1, invN, b2b, STATSK(4), N);
    gemm_mfma<true,true><<<rowTiles, 256, 0, stream>>>(
        b2b, WT(4), g1_b3, STATSK(4), g1_g2, g1_be2, invN, b0, STATSK(5), N);

    // decoder: ya/yb (bf16) from b0 with BN(5) folded into staging
    gemm_mfma<true,false><<<rowTiles, 256, 0, stream>>>(
        b0, WT(5), nullptr, STATSK(5), bn1_g, bn1_b, invN, b1b, nullptr, N);
    gemm_mfma<true,false><<<rowTiles, 256, 0, stream>>>(
        b0, WT(6), nullptr, STATSK(5), bn1_g, bn1_b, invN, b2b, nullptr, N);
    csr_stats<<<2048, 256, 0, stream>>>(b1b, b2b, rowoff, perm, lperm, wl, d_b1,
                                        STATSK(6), N, nspan);
    decoder_fused<<<edgeTiles, 256, 0, stream>>>(b1b, b2b, lperm, perm, dperm, eperm,
                                                 wl, d_b1, STATSK(6), d_g, d_be, invE,
                                                 w2t, d_b2, d_w3, d_b3, out, E);
}

// Round 12
// 1385.085 us; speedup vs baseline: 1.1359x; 1.1359x over previous
//
#include <hip/hip_runtime.h>
#include <hip/hip_bf16.h>
#include <math.h>

// ---------------------------------------------------------------------------
// GIN edge-attribute decoder.
// Round 11 -> 12: decoder reverted to the round-9 structure (per-tile blocks,
// W2 tile in LDS, bf16 ya/yb) — measured 244us. Round-10 persistent variant
// (300us: serialized staging) and round-11 register-W2 variant (425us:
// compiler sank the 16 w2t loads to MFMA use points, VGPR=68 proves breg was
// never register-resident) both regressed. Node pipeline keeps round-10 wins:
// all [N,128] intermediates bf16, BN folded into consumers, no bn_fin.
// Decoder trick: concat(x2[s],x2[d],l)@W1 == ya[s]+yb[d]+l*wl.
// ---------------------------------------------------------------------------

typedef __attribute__((ext_vector_type(8))) __bf16 bf16x8;
typedef __attribute__((ext_vector_type(4))) float f32x4;

__device__ __forceinline__ unsigned int pack_bf16(float a, float b) {
    unsigned short ua = __builtin_bit_cast(unsigned short, __float2bfloat16(a));
    unsigned short ub = __builtin_bit_cast(unsigned short, __float2bfloat16(b));
    return (unsigned int)ua | ((unsigned int)ub << 16);
}
__device__ __forceinline__ float bflo(unsigned int u) {
    return __builtin_bit_cast(float, u << 16);
}
__device__ __forceinline__ float bfhi(unsigned int u) {
    return __builtin_bit_cast(float, u & 0xffff0000u);
}
__device__ __forceinline__ unsigned short bf16r(float a) {
    return __builtin_bit_cast(unsigned short, __float2bfloat16(a));
}

// ---------------- CSR build ----------------

__global__ void hist_dst(const int* __restrict__ edst, int* __restrict__ cursor, int E) {
    int e = blockIdx.x * 256 + threadIdx.x;
    if (e < E) atomicAdd(&cursor[edst[e]], 1);
}

__global__ __launch_bounds__(1024) void scan_deg(const int* deg, int* rowoff, int* cursor, int N) {
    __shared__ int sums[1024];
    const int t = threadIdx.x;
    const int chunk = (N + 1023) >> 10;
    int lo = t * chunk, hi = lo + chunk;
    if (lo > N) lo = N;
    if (hi > N) hi = N;
    int s = 0;
    for (int i = lo; i < hi; ++i) s += deg[i];
    sums[t] = s;
    __syncthreads();
    for (int off = 1; off < 1024; off <<= 1) {
        int add = (t >= off) ? sums[t - off] : 0;
        __syncthreads();
        sums[t] += add;
        __syncthreads();
    }
    int run = sums[t] - s;
    for (int i = lo; i < hi; ++i) {
        int d = deg[i];
        rowoff[i] = run;
        cursor[i] = run;
        run += d;
    }
    if (t == 1023) rowoff[N] = sums[1023];
}

__global__ void fill_csr(const int* __restrict__ esrc, const int* __restrict__ edst,
                         const float* __restrict__ coords,
                         int* cursor, int* __restrict__ perm, int* __restrict__ dperm,
                         int* __restrict__ eperm, float* __restrict__ lperm, int E) {
    int e = blockIdx.x * 256 + threadIdx.x;
    if (e >= E) return;
    int s0 = esrc[e], d0 = edst[e];
    int pos = atomicAdd(&cursor[d0], 1);
    perm[pos] = s0;
    dperm[pos] = d0;
    eperm[pos] = e;
    float dx = coords[d0*3+0] - coords[s0*3+0];
    float dy = coords[d0*3+1] - coords[s0*3+1];
    float dz = coords[d0*3+2] - coords[s0*3+2];
    lperm[pos] = sqrtf(dx*dx + dy*dy + dz*dz);
}

// ---------------- gathers ----------------

__global__ void gather_coords(const float* __restrict__ coords,
                              const int* __restrict__ rowoff, const int* __restrict__ perm,
                              float* __restrict__ agg0, int N) {
    int i = blockIdx.x * 256 + threadIdx.x;
    if (i >= N) return;
    float ax = 0.f, ay = 0.f, az = 0.f;
    int b = rowoff[i], t = rowoff[i+1];
    for (int j = b; j < t; ++j) {
        int p = perm[j];
        ax += coords[p*3+0];
        ay += coords[p*3+1];
        az += coords[p*3+2];
    }
    agg0[i*3+0] = ax; agg0[i*3+1] = ay; agg0[i*3+2] = az;
}

// y[i] = (1+eps)*bnrelu(x[i]) + sum_j bnrelu(x[perm[j]]); x,y bf16; BN from raw stats
__global__ __launch_bounds__(256) void gather_combine_bn(const unsigned short* __restrict__ x,
                                                         const int* __restrict__ rowoff,
                                                         const int* __restrict__ perm,
                                                         const float* __restrict__ st,
                                                         const float* __restrict__ g,
                                                         const float* __restrict__ be,
                                                         float invN,
                                                         const float* __restrict__ eps,
                                                         unsigned short* __restrict__ y, int N) {
    int node = blockIdx.x * 4 + (threadIdx.x >> 6);
    int lane = threadIdx.x & 63;
    if (node >= N) return;
    float ep = 1.f + *eps;
    int c0 = lane*2, c1 = c0 + 1;
    float m0 = st[c0]*invN, m1 = st[c1]*invN;
    float v0 = fmaxf(st[128+c0]*invN - m0*m0, 0.f);
    float v1 = fmaxf(st[128+c1]*invN - m1*m1, 0.f);
    float a0 = g[c0]*rsqrtf(v0 + 1e-5f), a1 = g[c1]*rsqrtf(v1 + 1e-5f);
    float sx = a0, sy = a1;
    float hx = be[c0] - m0*a0, hy = be[c1] - m1*a1;
    const unsigned int* x2 = (const unsigned int*)x;
    int b = rowoff[node], t = rowoff[node+1];
    float accx = 0.f, accy = 0.f;
    int j = b;
    for (; j + 2 <= t; j += 2) {
        unsigned int u0 = x2[(size_t)perm[j]*64 + lane];
        unsigned int u1 = x2[(size_t)perm[j+1]*64 + lane];
        accx += fmaxf(fmaf(bflo(u0), sx, hx), 0.f) + fmaxf(fmaf(bflo(u1), sx, hx), 0.f);
        accy += fmaxf(fmaf(bfhi(u0), sy, hy), 0.f) + fmaxf(fmaf(bfhi(u1), sy, hy), 0.f);
    }
    if (j < t) {
        unsigned int u = x2[(size_t)perm[j]*64 + lane];
        accx += fmaxf(fmaf(bflo(u), sx, hx), 0.f);
        accy += fmaxf(fmaf(bfhi(u), sy, hy), 0.f);
    }
    unsigned int uo = x2[(size_t)node*64 + lane];
    accx = fmaf(ep, fmaxf(fmaf(bflo(uo), sx, hx), 0.f), accx);
    accy = fmaf(ep, fmaxf(fmaf(bfhi(uo), sy, hy), 0.f), accy);
    ((unsigned int*)y)[(size_t)node*64 + lane] = pack_bf16(accx, accy);
}

// ---------------- small kernels ----------------

__global__ __launch_bounds__(256) void lin0(const float* __restrict__ coords,
                                            const float* __restrict__ agg0,
                                            const float* __restrict__ W1,
                                            const float* __restrict__ b1,
                                            const float* __restrict__ eps0,
                                            unsigned short* __restrict__ t1,
                                            float* __restrict__ stats, int nrows) {
    int col = threadIdx.x & 127, half = threadIdx.x >> 7;
    float w0 = W1[col], w1 = W1[128+col], w2 = W1[256+col], bb = b1[col];
    float ep = 1.f + *eps0;
    float s = 0.f, q = 0.f;
    int r0 = blockIdx.x * 64;
    for (int i = 0; i < 32; ++i) {
        int row = r0 + half + 2*i;
        if (row < nrows) {
            float h0 = fmaf(ep, coords[row*3+0], agg0[row*3+0]);
            float h1 = fmaf(ep, coords[row*3+1], agg0[row*3+1]);
            float h2 = fmaf(ep, coords[row*3+2], agg0[row*3+2]);
            float v = fmaf(h0, w0, fmaf(h1, w1, fmaf(h2, w2, bb)));
            t1[row*128+col] = bf16r(v);
            s += v; q += v*v;
        }
    }
    __shared__ float red[512];
    red[half*128+col] = s;
    red[256 + half*128+col] = q;
    __syncthreads();
    if (threadIdx.x < 128) {
        atomicAdd(&stats[col],       red[col] + red[128+col]);
        atomicAdd(&stats[128+col],   red[256+col] + red[384+col]);
    }
}

// W2 [128][64] f32 -> w2t [64 cols][128 k] bf16 (decoder)
__global__ void prep_w2(const float* __restrict__ W2, unsigned short* __restrict__ w2t) {
    int i = blockIdx.x * 256 + threadIdx.x;
    if (i >= 128*64) return;
    int k = i >> 6, c = i & 63;
    w2t[c*128 + k] = bf16r(W2[i]);
}

// 7 node-GEMM weights [128][128] f32 -> [col][k] bf16
__global__ void prep_wT(const float* __restrict__ w0, const float* __restrict__ w1,
                        const float* __restrict__ w2, const float* __restrict__ w3,
                        const float* __restrict__ w4, const float* __restrict__ w5,
                        const float* __restrict__ w6, unsigned short* __restrict__ dst) {
    int m = blockIdx.y;
    const float* src = (m==0)?w0:(m==1)?w1:(m==2)?w2:(m==3)?w3:(m==4)?w4:(m==5)?w5:w6;
    int i = blockIdx.x * 256 + threadIdx.x;
    int k = i >> 7, c = i & 127;
    dst[m*16384 + c*128 + k] = bf16r(src[i]);
}

// ---------------- bf16 MFMA node GEMM: bf16 [N,128] @ [128,128] -> bf16 -----
template<bool IN_BN, bool STATS>
__global__ __launch_bounds__(256) void gemm_mfma(const unsigned short* __restrict__ A,
                                                 const unsigned short* __restrict__ wT,
                                                 const float* __restrict__ bias,
                                                 const float* __restrict__ inst,
                                                 const float* __restrict__ bng,
                                                 const float* __restrict__ bnb,
                                                 float invCnt,
                                                 unsigned short* __restrict__ Cb,
                                                 float* __restrict__ stats, int nrows) {
    __shared__ int4 sAi[1024];           // 16KB
    __shared__ int4 sBi[2048];           // 32KB
    __shared__ float sred[2][4][128];    // 4KB (sc/sh during staging)
    char* sA = (char*)sAi;
    char* sB = (char*)sBi;
    float* sSC = &sred[0][0][0];
    float* sSH = &sred[0][1][0];
    const int tid = threadIdx.x;
    const int tile0 = blockIdx.x * 64;

    if (IN_BN) {
        if (tid < 128) {
            float m = inst[tid] * invCnt;
            float v = fmaxf(inst[128+tid] * invCnt - m*m, 0.f);
            float a = bng[tid] * rsqrtf(v + 1e-5f);
            sSC[tid] = a;
            sSH[tid] = bnb[tid] - m*a;
        }
        __syncthreads();
    }

    // stage sB: wT [128 col][128 k] bf16 -> swizzled
    {
        const int4* src = (const int4*)wT;
        #pragma unroll
        for (int ii = 0; ii < 8; ++ii) {
            int s = tid + 256*ii;
            int col = s >> 4, k16 = s & 15;
            int byte = ((col << 8) + (k16 << 4)) ^ ((col & 7) << 4);
            *(int4*)(sB + byte) = src[s];
        }
    }
    // stage sA: bf16 rows (+optional BN/ReLU) -> swizzled. 1024 slots of 8 bf16.
    {
        const int4* A4 = (const int4*)A;   // 16 slots per row
        #pragma unroll
        for (int ii = 0; ii < 4; ++ii) {
            int s = tid + 256*ii;
            int r = s >> 4, k16 = s & 15;
            int row = tile0 + r;
            int4 raw = make_int4(0,0,0,0);
            if (row < nrows) raw = A4[(size_t)row*16 + k16];
            if (IN_BN) {
                float4 sa = ((const float4*)sSC)[k16*2];
                float4 sb = ((const float4*)sSC)[k16*2+1];
                float4 ha = ((const float4*)sSH)[k16*2];
                float4 hb = ((const float4*)sSH)[k16*2+1];
                unsigned int ux = raw.x, uy = raw.y, uz = raw.z, uw = raw.w;
                float e0 = fmaxf(fmaf(bflo(ux), sa.x, ha.x), 0.f);
                float e1 = fmaxf(fmaf(bfhi(ux), sa.y, ha.y), 0.f);
                float e2 = fmaxf(fmaf(bflo(uy), sa.z, ha.z), 0.f);
                float e3 = fmaxf(fmaf(bfhi(uy), sa.w, ha.w), 0.f);
                float e4 = fmaxf(fmaf(bflo(uz), sb.x, hb.x), 0.f);
                float e5 = fmaxf(fmaf(bfhi(uz), sb.y, hb.y), 0.f);
                float e6 = fmaxf(fmaf(bflo(uw), sb.z, hb.z), 0.f);
                float e7 = fmaxf(fmaf(bfhi(uw), sb.w, hb.w), 0.f);
                raw.x = (int)pack_bf16(e0, e1);
                raw.y = (int)pack_bf16(e2, e3);
                raw.z = (int)pack_bf16(e4, e5);
                raw.w = (int)pack_bf16(e6, e7);
            }
            int byte = ((r << 8) + (k16 << 4)) ^ ((r & 7) << 4);
            *(int4*)(sA + byte) = raw;
        }
    }
    __syncthreads();

    const int l = tid & 63;
    const int w = tid >> 6;
    const int arow = (w << 4) + (l & 15);
    const int kbase = (l >> 4) << 3;
    f32x4 accv[8];
    #pragma unroll
    for (int c = 0; c < 8; ++c) accv[c] = (f32x4){0.f, 0.f, 0.f, 0.f};

    #pragma unroll
    for (int t = 0; t < 4; ++t) {
        int k0 = t*32 + kbase;
        int abyte = ((arow << 8) + (k0 << 1)) ^ ((arow & 7) << 4);
        bf16x8 af = __builtin_bit_cast(bf16x8, *(const int4*)(sA + abyte));
        #pragma unroll
        for (int c = 0; c < 8; ++c) {
            int bcol = (c << 4) + (l & 15);
            int bbyte = ((bcol << 8) + (k0 << 1)) ^ ((bcol & 7) << 4);
            bf16x8 bf = __builtin_bit_cast(bf16x8, *(const int4*)(sB + bbyte));
            accv[c] = __builtin_amdgcn_mfma_f32_16x16x32_bf16(af, bf, accv[c], 0, 0, 0);
        }
    }

    const int rj = (l >> 4) << 2;
    float lsum[8], lsq[8];
    #pragma unroll
    for (int c = 0; c < 8; ++c) {
        int col = (c << 4) + (l & 15);
        float bv = bias ? bias[col] : 0.f;
        f32x4 a = accv[c];
        float s = 0.f, q = 0.f;
        #pragma unroll
        for (int j = 0; j < 4; ++j) {
            int row = tile0 + (w << 4) + rj + j;
            float o = a[j] + bv;
            if (row < nrows) {
                Cb[(size_t)row*128 + col] = bf16r(o);
                if (STATS) { s += o; q += o*o; }
            }
        }
        lsum[c] = s; lsq[c] = q;
    }
    if (STATS) {
        #pragma unroll
        for (int c = 0; c < 8; ++c) {
            lsum[c] += __shfl_xor(lsum[c], 16, 64);
            lsum[c] += __shfl_xor(lsum[c], 32, 64);
            lsq[c]  += __shfl_xor(lsq[c], 16, 64);
            lsq[c]  += __shfl_xor(lsq[c], 32, 64);
        }
        __syncthreads();
        if ((l >> 4) == 0) {
            #pragma unroll
            for (int c = 0; c < 8; ++c) {
                int col = (c << 4) + l;
                sred[0][w][col] = lsum[c];
                sred[1][w][col] = lsq[c];
            }
        }
        __syncthreads();
        if (tid < 128) {
            float s = sred[0][0][tid] + sred[0][1][tid] + sred[0][2][tid] + sred[0][3][tid];
            float q = sred[1][0][tid] + sred[1][1][tid] + sred[1][2][tid] + sred[1][3][tid];
            atomicAdd(&stats[tid], s);
            atomicAdd(&stats[128 + tid], q);
        }
    }
}

// -------- decoder BN stats (bf16 ya/yb), 2-edge unrolled gather -------------
__global__ __launch_bounds__(256) void csr_stats(const unsigned short* __restrict__ ya,
                                                 const unsigned short* __restrict__ yb,
                                                 const int* __restrict__ rowoff,
                                                 const int* __restrict__ perm,
                                                 const float* __restrict__ lperm,
                                                 const float* __restrict__ wl,
                                                 const float* __restrict__ b1,
                                                 float* __restrict__ stats, int N, int nspan) {
    int w = blockIdx.x * 4 + (threadIdx.x >> 6);
    int lane = threadIdx.x & 63;
    const unsigned int* ya2 = (const unsigned int*)ya;
    const unsigned int* yb2 = (const unsigned int*)yb;
    float2 wl2 = ((const float2*)wl)[lane];
    float2 b12 = ((const float2*)b1)[lane];
    float2 s = make_float2(0.f, 0.f), q = make_float2(0.f, 0.f);
    int i0 = w * nspan;
    int i1 = i0 + nspan; if (i1 > N) i1 = N;
    for (int i = i0; i < i1; ++i) {
        unsigned int ub = yb2[(size_t)i*64 + lane];
        float ybx = bflo(ub), yby = bfhi(ub);
        int b = rowoff[i], t = rowoff[i+1];
        int j = b;
        for (; j + 2 <= t; j += 2) {
            int p0 = perm[j], p1 = perm[j+1];
            float l0 = lperm[j], l1 = lperm[j+1];
            unsigned int ua0 = ya2[(size_t)p0*64 + lane];
            unsigned int ua1 = ya2[(size_t)p1*64 + lane];
            float z0x = bflo(ua0) + ybx + fmaf(l0, wl2.x, b12.x);
            float z0y = bfhi(ua0) + yby + fmaf(l0, wl2.y, b12.y);
            float z1x = bflo(ua1) + ybx + fmaf(l1, wl2.x, b12.x);
            float z1y = bfhi(ua1) + yby + fmaf(l1, wl2.y, b12.y);
            s.x += z0x + z1x; s.y += z0y + z1y;
            q.x += fmaf(z0x, z0x, z1x*z1x);
            q.y += fmaf(z0y, z0y, z1y*z1y);
        }
        if (j < t) {
            int p = perm[j];
            float lv = lperm[j];
            unsigned int ua = ya2[(size_t)p*64 + lane];
            float zx = bflo(ua) + ybx + fmaf(lv, wl2.x, b12.x);
            float zy = bfhi(ua) + yby + fmaf(lv, wl2.y, b12.y);
            s.x += zx; s.y += zy;
            q.x += zx*zx; q.y += zy*zy;
        }
    }
    __shared__ float red[1024];
    int wv = threadIdx.x >> 6;
    red[wv*128 + lane*2]       = s.x;
    red[wv*128 + lane*2 + 1]   = s.y;
    red[512 + wv*128 + lane*2]     = q.x;
    red[512 + wv*128 + lane*2 + 1] = q.y;
    __syncthreads();
    if (threadIdx.x < 128) {
        int c = threadIdx.x;
        float ss = red[c] + red[128+c] + red[256+c] + red[384+c];
        float qq = red[512+c] + red[640+c] + red[768+c] + red[896+c];
        atomicAdd(&stats[c], ss);
        atomicAdd(&stats[128+c], qq);
    }
}

// -------- fused decoder (round-9 structure): per-tile blocks, W2 in LDS -----
__global__ __launch_bounds__(256) void decoder_fused(const unsigned short* __restrict__ ya,
                                                     const unsigned short* __restrict__ yb,
                                                     const float* __restrict__ lperm,
                                                     const int* __restrict__ perm,
                                                     const int* __restrict__ dperm,
                                                     const int* __restrict__ eperm,
                                                     const float* __restrict__ wl,
                                                     const float* __restrict__ b1,
                                                     const float* __restrict__ st6,
                                                     const float* __restrict__ dg,
                                                     const float* __restrict__ dbe,
                                                     float invE,
                                                     const unsigned short* __restrict__ w2t,
                                                     const float* __restrict__ b2,
                                                     const float* __restrict__ w3,
                                                     const float* __restrict__ b3p,
                                                     float* __restrict__ out, int E) {
    __shared__ int4 sAB[2048];           // 32KB: [0,16K)=sA, [16K,32K)=sB
    char* sA = (char*)sAB;
    char* sB = (char*)sAB + 16384;
    const int tid = threadIdx.x;
    const int tile0 = blockIdx.x * 64;

    {
        const int4* src = (const int4*)w2t;
        #pragma unroll
        for (int ii = 0; ii < 4; ++ii) {
            int s = tid + 256*ii;
            int col = s >> 4, k16 = s & 15;
            int byte = ((col << 8) + (k16 << 4)) ^ ((col & 7) << 4);
            *(int4*)(sB + byte) = src[s];
        }
    }
    {
        const int c4 = tid & 31;
        const int rb = tid >> 5;
        float4 wv = ((const float4*)wl)[c4];
        float4 bb = ((const float4*)b1)[c4];
        float4 s4, t4;
        {
            int cb = c4 * 4;
            #pragma unroll
            for (int j = 0; j < 4; ++j) {
                float m = st6[cb+j] * invE;
                float v = fmaxf(st6[128+cb+j] * invE - m*m, 0.f);
                float a = dg[cb+j] * rsqrtf(v + 1e-5f);
                ((float*)&s4)[j] = a;
                ((float*)&t4)[j] = dbe[cb+j] - m*a;
            }
        }
        const uint2* ya2 = (const uint2*)ya;
        const uint2* yb2 = (const uint2*)yb;
        #pragma unroll
        for (int i = 0; i < 8; ++i) {
            int r = rb + 8*i;
            int row = tile0 + r;
            float4 v = make_float4(0.f, 0.f, 0.f, 0.f);
            if (row < E) {
                int s0 = perm[row], d0 = dperm[row];
                float lv = lperm[row];
                uint2 ua = ya2[(size_t)s0*32 + c4];
                uint2 ubv = yb2[(size_t)d0*32 + c4];
                float vax = bflo(ua.x), vay = bfhi(ua.x), vaz = bflo(ua.y), vaw = bfhi(ua.y);
                float vbx = bflo(ubv.x), vby = bfhi(ubv.x), vbz = bflo(ubv.y), vbw = bfhi(ubv.y);
                v.x = fmaxf(fmaf(vax + vbx + fmaf(lv, wv.x, bb.x), s4.x, t4.x), 0.f);
                v.y = fmaxf(fmaf(vay + vby + fmaf(lv, wv.y, bb.y), s4.y, t4.y), 0.f);
                v.z = fmaxf(fmaf(vaz + vbz + fmaf(lv, wv.z, bb.z), s4.z, t4.z), 0.f);
                v.w = fmaxf(fmaf(vaw + vbw + fmaf(lv, wv.w, bb.w), s4.w, t4.w), 0.f);
            }
            uint2 pk;
            pk.x = pack_bf16(v.x, v.y);
            pk.y = pack_bf16(v.z, v.w);
            int byte = ((r << 8) + (c4 << 3)) ^ ((r & 7) << 4);
            *(uint2*)(sA + byte) = pk;
        }
    }
    __syncthreads();

    const int l = tid & 63;
    const int w = tid >> 6;
    const int arow = (w << 4) + (l & 15);
    const int kbase = (l >> 4) << 3;
    f32x4 accv[4];
    #pragma unroll
    for (int c = 0; c < 4; ++c) accv[c] = (f32x4){0.f, 0.f, 0.f, 0.f};

    #pragma unroll
    for (int t = 0; t < 4; ++t) {
        int k0 = t*32 + kbase;
        int abyte = ((arow << 8) + (k0 << 1)) ^ ((arow & 7) << 4);
        bf16x8 af = __builtin_bit_cast(bf16x8, *(const int4*)(sA + abyte));
        #pragma unroll
        for (int c = 0; c < 4; ++c) {
            int bcol = (c << 4) + (l & 15);
            int bbyte = ((bcol << 8) + (k0 << 1)) ^ ((bcol & 7) << 4);
            bf16x8 bf = __builtin_bit_cast(bf16x8, *(const int4*)(sB + bbyte));
            accv[c] = __builtin_amdgcn_mfma_f32_16x16x32_bf16(af, bf, accv[c], 0, 0, 0);
        }
    }

    float p0 = 0.f, p1 = 0.f, p2 = 0.f, p3 = 0.f;
    #pragma unroll
    for (int c = 0; c < 4; ++c) {
        int col = (c << 4) + (l & 15);
        float b2c = b2[col], w3c = w3[col];
        f32x4 a = accv[c];
        p0 = fmaf(fmaxf(a[0] + b2c, 0.f), w3c, p0);
        p1 = fmaf(fmaxf(a[1] + b2c, 0.f), w3c, p1);
        p2 = fmaf(fmaxf(a[2] + b2c, 0.f), w3c, p2);
        p3 = fmaf(fmaxf(a[3] + b2c, 0.f), w3c, p3);
    }
    #pragma unroll
    for (int m = 1; m < 16; m <<= 1) {
        p0 += __shfl_xor(p0, m, 64);
        p1 += __shfl_xor(p1, m, 64);
        p2 += __shfl_xor(p2, m, 64);
        p3 += __shfl_xor(p3, m, 64);
    }
    if ((l & 15) == 0) {
        float b3v = b3p[0];
        int rbase = tile0 + (w << 4) + ((l >> 4) << 2);
        float pj[4] = {p0, p1, p2, p3};
        #pragma unroll
        for (int j = 0; j < 4; ++j) {
            int row = rbase + j;
            if (row < E) out[eperm[row]] = 1.f / (1.f + expf(-(pj[j] + b3v)));
        }
    }
}

// ---------------------------------------------------------------------------

extern "C" void kernel_launch(void* const* d_in, const int* in_sizes, int n_in,
                              void* d_out, int out_size, void* d_ws, size_t ws_size,
                              hipStream_t stream) {
    const int N = in_sizes[0] / 3;
    const int E = in_sizes[1] / 2;

    const float* coords = (const float*)d_in[0];
    const int*   ei     = (const int*)d_in[1];
    const int*   esrc = ei;
    const int*   edst = ei + E;
    const float* g0_w1 = (const float*)d_in[2];
    const float* g0_b1 = (const float*)d_in[3];
    const float* g0_g1 = (const float*)d_in[4];
    const float* g0_be1= (const float*)d_in[5];
    const float* g0_w2 = (const float*)d_in[6];
    const float* g0_b2 = (const float*)d_in[7];
    const float* g0_g2 = (const float*)d_in[8];
    const float* g0_be2= (const float*)d_in[9];
    const float* g0_w3 = (const float*)d_in[10];
    const float* g0_b3 = (const float*)d_in[11];
    const float* eps0  = (const float*)d_in[12];
    const float* bn0_g = (const float*)d_in[13];
    const float* bn0_b = (const float*)d_in[14];
    const float* g1_w1 = (const float*)d_in[15];
    const float* g1_b1 = (const float*)d_in[16];
    const float* g1_g1 = (const float*)d_in[17];
    const float* g1_be1= (const float*)d_in[18];
    const float* g1_w2 = (const float*)d_in[19];
    const float* g1_b2 = (const float*)d_in[20];
    const float* g1_g2 = (const float*)d_in[21];
    const float* g1_be2= (const float*)d_in[22];
    const float* g1_w3 = (const float*)d_in[23];
    const float* g1_b3 = (const float*)d_in[24];
    const float* eps1  = (const float*)d_in[25];
    const float* bn1_g = (const float*)d_in[26];
    const float* bn1_b = (const float*)d_in[27];
    const float* d_w1  = (const float*)d_in[28];
    const float* d_b1  = (const float*)d_in[29];
    const float* d_g   = (const float*)d_in[30];
    const float* d_be  = (const float*)d_in[31];
    const float* d_w2  = (const float*)d_in[32];
    const float* d_b2  = (const float*)d_in[33];
    const float* d_w3  = (const float*)d_in[34];
    const float* d_b3  = (const float*)d_in[35];

    float* ws = (float*)d_ws;
    const size_t NF = (size_t)N * 128;
    float* buf0 = ws;
    float* buf1 = ws + NF;
    float* buf2 = ws + 2*NF;
    float* agg0 = ws + 3*NF;                 // N*3
    float* stats= agg0 + (size_t)N*3;        // 7*256
    float* scsh = stats + 7*256;             // 7*256 (layout keep)
    float* lperm = scsh + 7*256;             // E
    int*   cursor = (int*)(lperm + E);       // N
    int*   rowoff = cursor + N;              // N+1
    int*   perm   = rowoff + N + 1;          // E
    int*   dperm  = perm + E;                // E
    int*   eperm  = dperm + E;               // E
    unsigned short* w2t = (unsigned short*)(eperm + E);  // 64*128 bf16
    unsigned short* wT  = w2t + 64*128;                  // 7 * 128*128 bf16

    unsigned short* b0 = (unsigned short*)buf0;
    unsigned short* b1b = (unsigned short*)buf1;
    unsigned short* b2b = (unsigned short*)buf2;

    float* out = (float*)d_out;

    const float* wl = d_w1 + 256*128;   // row 256 of d_w1

    #define STATSK(k) (stats + (k)*256)
    #define WT(m) (wT + (m)*16384)

    const int rowTiles = (N + 63) / 64;
    const int edgeTiles = (E + 63) / 64;
    const int eBlocks = (E + 255) / 256;
    const float invN = 1.f / (float)N;
    const float invE = 1.f / (float)E;
    const int nWaves = 2048 * 4;
    const int nspan = (N + nWaves - 1) / nWaves;

    hipMemsetAsync(stats, 0, 7*256 * sizeof(float), stream);
    hipMemsetAsync(cursor, 0, (size_t)N * sizeof(int), stream);

    // CSR build + weight prep
    hist_dst<<<eBlocks, 256, 0, stream>>>(edst, cursor, E);
    scan_deg<<<1, 1024, 0, stream>>>(cursor, rowoff, cursor, N);
    fill_csr<<<eBlocks, 256, 0, stream>>>(esrc, edst, coords, cursor, perm, dperm, eperm, lperm, E);
    prep_w2<<<32, 256, 0, stream>>>(d_w2, w2t);
    prep_wT<<<dim3(64, 7), 256, 0, stream>>>(g0_w2, g0_w3, g1_w1, g1_w2, g1_w3,
                                             d_w1, d_w1 + 128*128, wT);

    // layer 0
    gather_coords<<<(N + 255)/256, 256, 0, stream>>>(coords, rowoff, perm, agg0, N);
    lin0<<<rowTiles, 256, 0, stream>>>(coords, agg0, g0_w1, g0_b1, eps0, b0, STATSK(0), N);
    gemm_mfma<true,true><<<rowTiles, 256, 0, stream>>>(
        b0, WT(0), g0_b2, STATSK(0), g0_g1, g0_be1, invN, b1b, STATSK(1), N);
    gemm_mfma<true,true><<<rowTiles, 256, 0, stream>>>(
        b1b, WT(1), g0_b3, STATSK(1), g0_g2, g0_be2, invN, b2b, STATSK(2), N);

    // layer 1: h1 = (1+eps1)*bnrelu(t3) + gather(bnrelu(t3))
    gather_combine_bn<<<(N + 3)/4, 256, 0, stream>>>(
        b2b, rowoff, perm, STATSK(2), bn0_g, bn0_b, invN, eps1, b0, N);
    gemm_mfma<false,true><<<rowTiles, 256, 0, stream>>>(
        b0, WT(2), g1_b1, nullptr, nullptr, nullptr, 0.f, b1b, STATSK(3), N);
    gemm_mfma<true,true><<<rowTiles, 256, 0, stream>>>(
        b1b, WT(3), g1_b2, STATSK(3), g1_g1, g1_be1, invN, b2b, STATSK(4), N);
    gemm_mfma<true,true><<<rowTiles, 256, 0, stream>>>(
        b2b, WT(4), g1_b3, STATSK(4), g1_g2, g1_be2, invN, b0, STATSK(5), N);

    // decoder: ya/yb (bf16) from b0 with BN(5) folded into staging
    gemm_mfma<true,false><<<rowTiles, 256, 0, stream>>>(
        b0, WT(5), nullptr, STATSK(5), bn1_g, bn1_b, invN, b1b, nullptr, N);
    gemm_mfma<true,false><<<rowTiles, 256, 0, stream>>>(
        b0, WT(6), nullptr, STATSK(5), bn1_g, bn1_b, invN, b2b, nullptr, N);
    csr_stats<<<2048, 256, 0, stream>>>(b1b, b2b, rowoff, perm, lperm, wl, d_b1,
                                        STATSK(6), N, nspan);
    decoder_fused<<<edgeTiles, 256, 0, stream>>>(b1b, b2b, lperm, perm, dperm, eperm,
                                                 wl, d_b1, STATSK(6), d_g, d_be, invE,
                                                 w2t, d_b2, d_w3, d_b3, out, E);
}

// Round 14
// 1291.032 us; speedup vs baseline: 1.2186x; 1.0729x over previous
//
#include <hip/hip_runtime.h>
#include <hip/hip_bf16.h>
#include <math.h>

// ---------------------------------------------------------------------------
// GIN edge-attribute decoder.
// Round 12 -> 13 (resubmitted; round 13 bench was an infra failure):
// gather kernels are LLC-latency-bound (decoder: 213MB L2-miss @1.1TB/s,
// occ 44%) -> attack latency hiding. (1) decoder_fused: 512 thr, 128-edge
// tiles, 48KB LDS -> 3 blocks/CU x 8 waves = 75% occupancy (was 44%).
// (2) csr_stats + gather_combine_bn: 4-edge-unrolled gathers (4 independent
// loads in flight). Node pipeline unchanged (bf16 intermediates, BN folded,
// round-9-structure decoder tile layout).
// Decoder trick: concat(x2[s],x2[d],l)@W1 == ya[s]+yb[d]+l*wl.
// ---------------------------------------------------------------------------

typedef __attribute__((ext_vector_type(8))) __bf16 bf16x8;
typedef __attribute__((ext_vector_type(4))) float f32x4;

__device__ __forceinline__ unsigned int pack_bf16(float a, float b) {
    unsigned short ua = __builtin_bit_cast(unsigned short, __float2bfloat16(a));
    unsigned short ub = __builtin_bit_cast(unsigned short, __float2bfloat16(b));
    return (unsigned int)ua | ((unsigned int)ub << 16);
}
__device__ __forceinline__ float bflo(unsigned int u) {
    return __builtin_bit_cast(float, u << 16);
}
__device__ __forceinline__ float bfhi(unsigned int u) {
    return __builtin_bit_cast(float, u & 0xffff0000u);
}
__device__ __forceinline__ unsigned short bf16r(float a) {
    return __builtin_bit_cast(unsigned short, __float2bfloat16(a));
}

// ---------------- CSR build ----------------

__global__ void hist_dst(const int* __restrict__ edst, int* __restrict__ cursor, int E) {
    int e = blockIdx.x * 256 + threadIdx.x;
    if (e < E) atomicAdd(&cursor[edst[e]], 1);
}

__global__ __launch_bounds__(1024) void scan_deg(const int* deg, int* rowoff, int* cursor, int N) {
    __shared__ int sums[1024];
    const int t = threadIdx.x;
    const int chunk = (N + 1023) >> 10;
    int lo = t * chunk, hi = lo + chunk;
    if (lo > N) lo = N;
    if (hi > N) hi = N;
    int s = 0;
    for (int i = lo; i < hi; ++i) s += deg[i];
    sums[t] = s;
    __syncthreads();
    for (int off = 1; off < 1024; off <<= 1) {
        int add = (t >= off) ? sums[t - off] : 0;
        __syncthreads();
        sums[t] += add;
        __syncthreads();
    }
    int run = sums[t] - s;
    for (int i = lo; i < hi; ++i) {
        int d = deg[i];
        rowoff[i] = run;
        cursor[i] = run;
        run += d;
    }
    if (t == 1023) rowoff[N] = sums[1023];
}

__global__ void fill_csr(const int* __restrict__ esrc, const int* __restrict__ edst,
                         const float* __restrict__ coords,
                         int* cursor, int* __restrict__ perm, int* __restrict__ dperm,
                         int* __restrict__ eperm, float* __restrict__ lperm, int E) {
    int e = blockIdx.x * 256 + threadIdx.x;
    if (e >= E) return;
    int s0 = esrc[e], d0 = edst[e];
    int pos = atomicAdd(&cursor[d0], 1);
    perm[pos] = s0;
    dperm[pos] = d0;
    eperm[pos] = e;
    float dx = coords[d0*3+0] - coords[s0*3+0];
    float dy = coords[d0*3+1] - coords[s0*3+1];
    float dz = coords[d0*3+2] - coords[s0*3+2];
    lperm[pos] = sqrtf(dx*dx + dy*dy + dz*dz);
}

// ---------------- gathers ----------------

__global__ void gather_coords(const float* __restrict__ coords,
                              const int* __restrict__ rowoff, const int* __restrict__ perm,
                              float* __restrict__ agg0, int N) {
    int i = blockIdx.x * 256 + threadIdx.x;
    if (i >= N) return;
    float ax = 0.f, ay = 0.f, az = 0.f;
    int b = rowoff[i], t = rowoff[i+1];
    for (int j = b; j < t; ++j) {
        int p = perm[j];
        ax += coords[p*3+0];
        ay += coords[p*3+1];
        az += coords[p*3+2];
    }
    agg0[i*3+0] = ax; agg0[i*3+1] = ay; agg0[i*3+2] = az;
}

// y[i] = (1+eps)*bnrelu(x[i]) + sum_j bnrelu(x[perm[j]]); x,y bf16; 4-deep pipe
__global__ __launch_bounds__(256) void gather_combine_bn(const unsigned short* __restrict__ x,
                                                         const int* __restrict__ rowoff,
                                                         const int* __restrict__ perm,
                                                         const float* __restrict__ st,
                                                         const float* __restrict__ g,
                                                         const float* __restrict__ be,
                                                         float invN,
                                                         const float* __restrict__ eps,
                                                         unsigned short* __restrict__ y, int N) {
    int node = blockIdx.x * 4 + (threadIdx.x >> 6);
    int lane = threadIdx.x & 63;
    if (node >= N) return;
    float ep = 1.f + *eps;
    int c0 = lane*2, c1 = c0 + 1;
    float m0 = st[c0]*invN, m1 = st[c1]*invN;
    float v0 = fmaxf(st[128+c0]*invN - m0*m0, 0.f);
    float v1 = fmaxf(st[128+c1]*invN - m1*m1, 0.f);
    float sx = g[c0]*rsqrtf(v0 + 1e-5f), sy = g[c1]*rsqrtf(v1 + 1e-5f);
    float hx = be[c0] - m0*sx, hy = be[c1] - m1*sy;
    const unsigned int* x2 = (const unsigned int*)x;
    int b = rowoff[node], t = rowoff[node+1];
    float accx = 0.f, accy = 0.f;
    int j = b;
    for (; j + 4 <= t; j += 4) {
        unsigned int u0 = x2[(size_t)perm[j]*64 + lane];
        unsigned int u1 = x2[(size_t)perm[j+1]*64 + lane];
        unsigned int u2 = x2[(size_t)perm[j+2]*64 + lane];
        unsigned int u3 = x2[(size_t)perm[j+3]*64 + lane];
        accx += fmaxf(fmaf(bflo(u0), sx, hx), 0.f) + fmaxf(fmaf(bflo(u1), sx, hx), 0.f)
              + fmaxf(fmaf(bflo(u2), sx, hx), 0.f) + fmaxf(fmaf(bflo(u3), sx, hx), 0.f);
        accy += fmaxf(fmaf(bfhi(u0), sy, hy), 0.f) + fmaxf(fmaf(bfhi(u1), sy, hy), 0.f)
              + fmaxf(fmaf(bfhi(u2), sy, hy), 0.f) + fmaxf(fmaf(bfhi(u3), sy, hy), 0.f);
    }
    for (; j < t; ++j) {
        unsigned int u = x2[(size_t)perm[j]*64 + lane];
        accx += fmaxf(fmaf(bflo(u), sx, hx), 0.f);
        accy += fmaxf(fmaf(bfhi(u), sy, hy), 0.f);
    }
    unsigned int uo = x2[(size_t)node*64 + lane];
    accx = fmaf(ep, fmaxf(fmaf(bflo(uo), sx, hx), 0.f), accx);
    accy = fmaf(ep, fmaxf(fmaf(bfhi(uo), sy, hy), 0.f), accy);
    ((unsigned int*)y)[(size_t)node*64 + lane] = pack_bf16(accx, accy);
}

// ---------------- small kernels ----------------

__global__ __launch_bounds__(256) void lin0(const float* __restrict__ coords,
                                            const float* __restrict__ agg0,
                                            const float* __restrict__ W1,
                                            const float* __restrict__ b1,
                                            const float* __restrict__ eps0,
                                            unsigned short* __restrict__ t1,
                                            float* __restrict__ stats, int nrows) {
    int col = threadIdx.x & 127, half = threadIdx.x >> 7;
    float w0 = W1[col], w1 = W1[128+col], w2 = W1[256+col], bb = b1[col];
    float ep = 1.f + *eps0;
    float s = 0.f, q = 0.f;
    int r0 = blockIdx.x * 64;
    for (int i = 0; i < 32; ++i) {
        int row = r0 + half + 2*i;
        if (row < nrows) {
            float h0 = fmaf(ep, coords[row*3+0], agg0[row*3+0]);
            float h1 = fmaf(ep, coords[row*3+1], agg0[row*3+1]);
            float h2 = fmaf(ep, coords[row*3+2], agg0[row*3+2]);
            float v = fmaf(h0, w0, fmaf(h1, w1, fmaf(h2, w2, bb)));
            t1[row*128+col] = bf16r(v);
            s += v; q += v*v;
        }
    }
    __shared__ float red[512];
    red[half*128+col] = s;
    red[256 + half*128+col] = q;
    __syncthreads();
    if (threadIdx.x < 128) {
        atomicAdd(&stats[col],       red[col] + red[128+col]);
        atomicAdd(&stats[128+col],   red[256+col] + red[384+col]);
    }
}

// W2 [128][64] f32 -> w2t [64 cols][128 k] bf16 (decoder)
__global__ void prep_w2(const float* __restrict__ W2, unsigned short* __restrict__ w2t) {
    int i = blockIdx.x * 256 + threadIdx.x;
    if (i >= 128*64) return;
    int k = i >> 6, c = i & 63;
    w2t[c*128 + k] = bf16r(W2[i]);
}

// 7 node-GEMM weights [128][128] f32 -> [col][k] bf16
__global__ void prep_wT(const float* __restrict__ w0, const float* __restrict__ w1,
                        const float* __restrict__ w2, const float* __restrict__ w3,
                        const float* __restrict__ w4, const float* __restrict__ w5,
                        const float* __restrict__ w6, unsigned short* __restrict__ dst) {
    int m = blockIdx.y;
    const float* src = (m==0)?w0:(m==1)?w1:(m==2)?w2:(m==3)?w3:(m==4)?w4:(m==5)?w5:w6;
    int i = blockIdx.x * 256 + threadIdx.x;
    int k = i >> 7, c = i & 127;
    dst[m*16384 + c*128 + k] = bf16r(src[i]);
}

// ---------------- bf16 MFMA node GEMM: bf16 [N,128] @ [128,128] -> bf16 -----
template<bool IN_BN, bool STATS>
__global__ __launch_bounds__(256) void gemm_mfma(const unsigned short* __restrict__ A,
                                                 const unsigned short* __restrict__ wT,
                                                 const float* __restrict__ bias,
                                                 const float* __restrict__ inst,
                                                 const float* __restrict__ bng,
                                                 const float* __restrict__ bnb,
                                                 float invCnt,
                                                 unsigned short* __restrict__ Cb,
                                                 float* __restrict__ stats, int nrows) {
    __shared__ int4 sAi[1024];           // 16KB
    __shared__ int4 sBi[2048];           // 32KB
    __shared__ float sred[2][4][128];    // 4KB (sc/sh during staging)
    char* sA = (char*)sAi;
    char* sB = (char*)sBi;
    float* sSC = &sred[0][0][0];
    float* sSH = &sred[0][1][0];
    const int tid = threadIdx.x;
    const int tile0 = blockIdx.x * 64;

    if (IN_BN) {
        if (tid < 128) {
            float m = inst[tid] * invCnt;
            float v = fmaxf(inst[128+tid] * invCnt - m*m, 0.f);
            float a = bng[tid] * rsqrtf(v + 1e-5f);
            sSC[tid] = a;
            sSH[tid] = bnb[tid] - m*a;
        }
        __syncthreads();
    }

    // stage sB: wT [128 col][128 k] bf16 -> swizzled
    {
        const int4* src = (const int4*)wT;
        #pragma unroll
        for (int ii = 0; ii < 8; ++ii) {
            int s = tid + 256*ii;
            int col = s >> 4, k16 = s & 15;
            int byte = ((col << 8) + (k16 << 4)) ^ ((col & 7) << 4);
            *(int4*)(sB + byte) = src[s];
        }
    }
    // stage sA: bf16 rows (+optional BN/ReLU) -> swizzled. 1024 slots of 8 bf16.
    {
        const int4* A4 = (const int4*)A;   // 16 slots per row
        #pragma unroll
        for (int ii = 0; ii < 4; ++ii) {
            int s = tid + 256*ii;
            int r = s >> 4, k16 = s & 15;
            int row = tile0 + r;
            int4 raw = make_int4(0,0,0,0);
            if (row < nrows) raw = A4[(size_t)row*16 + k16];
            if (IN_BN) {
                float4 sa = ((const float4*)sSC)[k16*2];
                float4 sb = ((const float4*)sSC)[k16*2+1];
                float4 ha = ((const float4*)sSH)[k16*2];
                float4 hb = ((const float4*)sSH)[k16*2+1];
                unsigned int ux = raw.x, uy = raw.y, uz = raw.z, uw = raw.w;
                float e0 = fmaxf(fmaf(bflo(ux), sa.x, ha.x), 0.f);
                float e1 = fmaxf(fmaf(bfhi(ux), sa.y, ha.y), 0.f);
                float e2 = fmaxf(fmaf(bflo(uy), sa.z, ha.z), 0.f);
                float e3 = fmaxf(fmaf(bfhi(uy), sa.w, ha.w), 0.f);
                float e4 = fmaxf(fmaf(bflo(uz), sb.x, hb.x), 0.f);
                float e5 = fmaxf(fmaf(bfhi(uz), sb.y, hb.y), 0.f);
                float e6 = fmaxf(fmaf(bflo(uw), sb.z, hb.z), 0.f);
                float e7 = fmaxf(fmaf(bfhi(uw), sb.w, hb.w), 0.f);
                raw.x = (int)pack_bf16(e0, e1);
                raw.y = (int)pack_bf16(e2, e3);
                raw.z = (int)pack_bf16(e4, e5);
                raw.w = (int)pack_bf16(e6, e7);
            }
            int byte = ((r << 8) + (k16 << 4)) ^ ((r & 7) << 4);
            *(int4*)(sA + byte) = raw;
        }
    }
    __syncthreads();

    const int l = tid & 63;
    const int w = tid >> 6;
    const int arow = (w << 4) + (l & 15);
    const int kbase = (l >> 4) << 3;
    f32x4 accv[8];
    #pragma unroll
    for (int c = 0; c < 8; ++c) accv[c] = (f32x4){0.f, 0.f, 0.f, 0.f};

    #pragma unroll
    for (int t = 0; t < 4; ++t) {
        int k0 = t*32 + kbase;
        int abyte = ((arow << 8) + (k0 << 1)) ^ ((arow & 7) << 4);
        bf16x8 af = __builtin_bit_cast(bf16x8, *(const int4*)(sA + abyte));
        #pragma unroll
        for (int c = 0; c < 8; ++c) {
            int bcol = (c << 4) + (l & 15);
            int bbyte = ((bcol << 8) + (k0 << 1)) ^ ((bcol & 7) << 4);
            bf16x8 bf = __builtin_bit_cast(bf16x8, *(const int4*)(sB + bbyte));
            accv[c] = __builtin_amdgcn_mfma_f32_16x16x32_bf16(af, bf, accv[c], 0, 0, 0);
        }
    }

    const int rj = (l >> 4) << 2;
    float lsum[8], lsq[8];
    #pragma unroll
    for (int c = 0; c < 8; ++c) {
        int col = (c << 4) + (l & 15);
        float bv = bias ? bias[col] : 0.f;
        f32x4 a = accv[c];
        float s = 0.f, q = 0.f;
        #pragma unroll
        for (int j = 0; j < 4; ++j) {
            int row = tile0 + (w << 4) + rj + j;
            float o = a[j] + bv;
            if (row < nrows) {
                Cb[(size_t)row*128 + col] = bf16r(o);
                if (STATS) { s += o; q += o*o; }
            }
        }
        lsum[c] = s; lsq[c] = q;
    }
    if (STATS) {
        #pragma unroll
        for (int c = 0; c < 8; ++c) {
            lsum[c] += __shfl_xor(lsum[c], 16, 64);
            lsum[c] += __shfl_xor(lsum[c], 32, 64);
            lsq[c]  += __shfl_xor(lsq[c], 16, 64);
            lsq[c]  += __shfl_xor(lsq[c], 32, 64);
        }
        __syncthreads();
        if ((l >> 4) == 0) {
            #pragma unroll
            for (int c = 0; c < 8; ++c) {
                int col = (c << 4) + l;
                sred[0][w][col] = lsum[c];
                sred[1][w][col] = lsq[c];
            }
        }
        __syncthreads();
        if (tid < 128) {
            float s = sred[0][0][tid] + sred[0][1][tid] + sred[0][2][tid] + sred[0][3][tid];
            float q = sred[1][0][tid] + sred[1][1][tid] + sred[1][2][tid] + sred[1][3][tid];
            atomicAdd(&stats[tid], s);
            atomicAdd(&stats[128 + tid], q);
        }
    }
}

// -------- decoder BN stats (bf16 ya/yb), 4-edge unrolled gather -------------
__global__ __launch_bounds__(256) void csr_stats(const unsigned short* __restrict__ ya,
                                                 const unsigned short* __restrict__ yb,
                                                 const int* __restrict__ rowoff,
                                                 const int* __restrict__ perm,
                                                 const float* __restrict__ lperm,
                                                 const float* __restrict__ wl,
                                                 const float* __restrict__ b1,
                                                 float* __restrict__ stats, int N, int nspan) {
    int w = blockIdx.x * 4 + (threadIdx.x >> 6);
    int lane = threadIdx.x & 63;
    const unsigned int* ya2 = (const unsigned int*)ya;
    const unsigned int* yb2 = (const unsigned int*)yb;
    float2 wl2 = ((const float2*)wl)[lane];
    float2 b12 = ((const float2*)b1)[lane];
    float2 s = make_float2(0.f, 0.f), q = make_float2(0.f, 0.f);
    int i0 = w * nspan;
    int i1 = i0 + nspan; if (i1 > N) i1 = N;
    for (int i = i0; i < i1; ++i) {
        unsigned int ub = yb2[(size_t)i*64 + lane];
        float ybx = bflo(ub), yby = bfhi(ub);
        int b = rowoff[i], t = rowoff[i+1];
        int j = b;
        for (; j + 4 <= t; j += 4) {
            int p0 = perm[j], p1 = perm[j+1], p2 = perm[j+2], p3 = perm[j+3];
            float l0 = lperm[j], l1 = lperm[j+1], l2 = lperm[j+2], l3 = lperm[j+3];
            unsigned int ua0 = ya2[(size_t)p0*64 + lane];
            unsigned int ua1 = ya2[(size_t)p1*64 + lane];
            unsigned int ua2 = ya2[(size_t)p2*64 + lane];
            unsigned int ua3 = ya2[(size_t)p3*64 + lane];
            float z0x = bflo(ua0) + ybx + fmaf(l0, wl2.x, b12.x);
            float z0y = bfhi(ua0) + yby + fmaf(l0, wl2.y, b12.y);
            float z1x = bflo(ua1) + ybx + fmaf(l1, wl2.x, b12.x);
            float z1y = bfhi(ua1) + yby + fmaf(l1, wl2.y, b12.y);
            float z2x = bflo(ua2) + ybx + fmaf(l2, wl2.x, b12.x);
            float z2y = bfhi(ua2) + yby + fmaf(l2, wl2.y, b12.y);
            float z3x = bflo(ua3) + ybx + fmaf(l3, wl2.x, b12.x);
            float z3y = bfhi(ua3) + yby + fmaf(l3, wl2.y, b12.y);
            s.x += (z0x + z1x) + (z2x + z3x);
            s.y += (z0y + z1y) + (z2y + z3y);
            q.x += fmaf(z0x, z0x, z1x*z1x) + fmaf(z2x, z2x, z3x*z3x);
            q.y += fmaf(z0y, z0y, z1y*z1y) + fmaf(z2y, z2y, z3y*z3y);
        }
        for (; j < t; ++j) {
            int p = perm[j];
            float lv = lperm[j];
            unsigned int ua = ya2[(size_t)p*64 + lane];
            float zx = bflo(ua) + ybx + fmaf(lv, wl2.x, b12.x);
            float zy = bfhi(ua) + yby + fmaf(lv, wl2.y, b12.y);
            s.x += zx; s.y += zy;
            q.x += zx*zx; q.y += zy*zy;
        }
    }
    __shared__ float red[1024];
    int wv = threadIdx.x >> 6;
    red[wv*128 + lane*2]       = s.x;
    red[wv*128 + lane*2 + 1]   = s.y;
    red[512 + wv*128 + lane*2]     = q.x;
    red[512 + wv*128 + lane*2 + 1] = q.y;
    __syncthreads();
    if (threadIdx.x < 128) {
        int c = threadIdx.x;
        float ss = red[c] + red[128+c] + red[256+c] + red[384+c];
        float qq = red[512+c] + red[640+c] + red[768+c] + red[896+c];
        atomicAdd(&stats[c], ss);
        atomicAdd(&stats[128+c], qq);
    }
}

// -------- fused decoder: 512 thr, 128-edge tiles, 48KB LDS (75% occ) --------
__global__ __launch_bounds__(512) void decoder_fused(const unsigned short* __restrict__ ya,
                                                     const unsigned short* __restrict__ yb,
                                                     const float* __restrict__ lperm,
                                                     const int* __restrict__ perm,
                                                     const int* __restrict__ dperm,
                                                     const int* __restrict__ eperm,
                                                     const float* __restrict__ wl,
                                                     const float* __restrict__ b1,
                                                     const float* __restrict__ st6,
                                                     const float* __restrict__ dg,
                                                     const float* __restrict__ dbe,
                                                     float invE,
                                                     const unsigned short* __restrict__ w2t,
                                                     const float* __restrict__ b2,
                                                     const float* __restrict__ w3,
                                                     const float* __restrict__ b3p,
                                                     float* __restrict__ out, int E) {
    __shared__ int4 sAi[2048];           // 32KB: z tile [128 rows][128 bf16]
    __shared__ int4 sBi[1024];           // 16KB: W2^T [64 col][128 k]
    char* sA = (char*)sAi;
    char* sB = (char*)sBi;
    const int tid = threadIdx.x;
    const int tile0 = blockIdx.x * 128;

    // stage sB (1024 slots, 512 threads x 2)
    {
        const int4* src = (const int4*)w2t;
        #pragma unroll
        for (int ii = 0; ii < 2; ++ii) {
            int s = tid + 512*ii;
            int col = s >> 4, k16 = s & 15;
            int byte = ((col << 8) + (k16 << 4)) ^ ((col & 7) << 4);
            *(int4*)(sB + byte) = src[s];
        }
    }
    // stage sA: z = bnrelu(ya[s]+yb[d]+l*wl+b1) -> bf16, swizzled; 128 rows
    {
        const int c4 = tid & 31;
        const int rb = tid >> 5;        // 0..15
        float4 wv = ((const float4*)wl)[c4];
        float4 bb = ((const float4*)b1)[c4];
        float4 s4, t4;
        {
            int cb = c4 * 4;
            #pragma unroll
            for (int j = 0; j < 4; ++j) {
                float m = st6[cb+j] * invE;
                float v = fmaxf(st6[128+cb+j] * invE - m*m, 0.f);
                float a = dg[cb+j] * rsqrtf(v + 1e-5f);
                ((float*)&s4)[j] = a;
                ((float*)&t4)[j] = dbe[cb+j] - m*a;
            }
        }
        const uint2* ya2 = (const uint2*)ya;
        const uint2* yb2 = (const uint2*)yb;
        #pragma unroll
        for (int i = 0; i < 8; ++i) {
            int r = rb + 16*i;          // 0..127
            int row = tile0 + r;
            float4 v = make_float4(0.f, 0.f, 0.f, 0.f);
            if (row < E) {
                int s0 = perm[row], d0 = dperm[row];
                float lv = lperm[row];
                uint2 ua = ya2[(size_t)s0*32 + c4];
                uint2 ubv = yb2[(size_t)d0*32 + c4];
                float vax = bflo(ua.x), vay = bfhi(ua.x), vaz = bflo(ua.y), vaw = bfhi(ua.y);
                float vbx = bflo(ubv.x), vby = bfhi(ubv.x), vbz = bflo(ubv.y), vbw = bfhi(ubv.y);
                v.x = fmaxf(fmaf(vax + vbx + fmaf(lv, wv.x, bb.x), s4.x, t4.x), 0.f);
                v.y = fmaxf(fmaf(vay + vby + fmaf(lv, wv.y, bb.y), s4.y, t4.y), 0.f);
                v.z = fmaxf(fmaf(vaz + vbz + fmaf(lv, wv.z, bb.z), s4.z, t4.z), 0.f);
                v.w = fmaxf(fmaf(vaw + vbw + fmaf(lv, wv.w, bb.w), s4.w, t4.w), 0.f);
            }
            uint2 pk;
            pk.x = pack_bf16(v.x, v.y);
            pk.y = pack_bf16(v.z, v.w);
            int byte = ((r << 8) + (c4 << 3)) ^ ((r & 7) << 4);
            *(uint2*)(sA + byte) = pk;
        }
    }
    __syncthreads();

    const int l = tid & 63;
    const int w = tid >> 6;             // 0..7, wave w owns rows 16w..16w+15
    const int arow = (w << 4) + (l & 15);
    const int kbase = (l >> 4) << 3;
    f32x4 accv[4];
    #pragma unroll
    for (int c = 0; c < 4; ++c) accv[c] = (f32x4){0.f, 0.f, 0.f, 0.f};

    #pragma unroll
    for (int t = 0; t < 4; ++t) {
        int k0 = t*32 + kbase;
        int abyte = ((arow << 8) + (k0 << 1)) ^ ((arow & 7) << 4);
        bf16x8 af = __builtin_bit_cast(bf16x8, *(const int4*)(sA + abyte));
        #pragma unroll
        for (int c = 0; c < 4; ++c) {
            int bcol = (c << 4) + (l & 15);
            int bbyte = ((bcol << 8) + (k0 << 1)) ^ ((bcol & 7) << 4);
            bf16x8 bf = __builtin_bit_cast(bf16x8, *(const int4*)(sB + bbyte));
            accv[c] = __builtin_amdgcn_mfma_f32_16x16x32_bf16(af, bf, accv[c], 0, 0, 0);
        }
    }

    float p0 = 0.f, p1 = 0.f, p2 = 0.f, p3 = 0.f;
    #pragma unroll
    for (int c = 0; c < 4; ++c) {
        int col = (c << 4) + (l & 15);
        float b2c = b2[col], w3c = w3[col];
        f32x4 a = accv[c];
        p0 = fmaf(fmaxf(a[0] + b2c, 0.f), w3c, p0);
        p1 = fmaf(fmaxf(a[1] + b2c, 0.f), w3c, p1);
        p2 = fmaf(fmaxf(a[2] + b2c, 0.f), w3c, p2);
        p3 = fmaf(fmaxf(a[3] + b2c, 0.f), w3c, p3);
    }
    #pragma unroll
    for (int m = 1; m < 16; m <<= 1) {
        p0 += __shfl_xor(p0, m, 64);
        p1 += __shfl_xor(p1, m, 64);
        p2 += __shfl_xor(p2, m, 64);
        p3 += __shfl_xor(p3, m, 64);
    }
    if ((l & 15) == 0) {
        float b3v = b3p[0];
        int rbase = tile0 + (w << 4) + ((l >> 4) << 2);
        float pj[4] = {p0, p1, p2, p3};
        #pragma unroll
        for (int j = 0; j < 4; ++j) {
            int row = rbase + j;
            if (row < E) out[eperm[row]] = 1.f / (1.f + expf(-(pj[j] + b3v)));
        }
    }
}

// ---------------------------------------------------------------------------

extern "C" void kernel_launch(void* const* d_in, const int* in_sizes, int n_in,
                              void* d_out, int out_size, void* d_ws, size_t ws_size,
                              hipStream_t stream) {
    const int N = in_sizes[0] / 3;
    const int E = in_sizes[1] / 2;

    const float* coords = (const float*)d_in[0];
    const int*   ei     = (const int*)d_in[1];
    const int*   esrc = ei;
    const int*   edst = ei + E;
    const float* g0_w1 = (const float*)d_in[2];
    const float* g0_b1 = (const float*)d_in[3];
    const float* g0_g1 = (const float*)d_in[4];
    const float* g0_be1= (const float*)d_in[5];
    const float* g0_w2 = (const float*)d_in[6];
    const float* g0_b2 = (const float*)d_in[7];
    const float* g0_g2 = (const float*)d_in[8];
    const float* g0_be2= (const float*)d_in[9];
    const float* g0_w3 = (const float*)d_in[10];
    const float* g0_b3 = (const float*)d_in[11];
    const float* eps0  = (const float*)d_in[12];
    const float* bn0_g = (const float*)d_in[13];
    const float* bn0_b = (const float*)d_in[14];
    const float* g1_w1 = (const float*)d_in[15];
    const float* g1_b1 = (const float*)d_in[16];
    const float* g1_g1 = (const float*)d_in[17];
    const float* g1_be1= (const float*)d_in[18];
    const float* g1_w2 = (const float*)d_in[19];
    const float* g1_b2 = (const float*)d_in[20];
    const float* g1_g2 = (const float*)d_in[21];
    const float* g1_be2= (const float*)d_in[22];
    const float* g1_w3 = (const float*)d_in[23];
    const float* g1_b3 = (const float*)d_in[24];
    const float* eps1  = (const float*)d_in[25];
    const float* bn1_g = (const float*)d_in[26];
    const float* bn1_b = (const float*)d_in[27];
    const float* d_w1  = (const float*)d_in[28];
    const float* d_b1  = (const float*)d_in[29];
    const float* d_g   = (const float*)d_in[30];
    const float* d_be  = (const float*)d_in[31];
    const float* d_w2  = (const float*)d_in[32];
    const float* d_b2  = (const float*)d_in[33];
    const float* d_w3  = (const float*)d_in[34];
    const float* d_b3  = (const float*)d_in[35];

    float* ws = (float*)d_ws;
    const size_t NF = (size_t)N * 128;
    float* buf0 = ws;
    float* buf1 = ws + NF;
    float* buf2 = ws + 2*NF;
    float* agg0 = ws + 3*NF;                 // N*3
    float* stats= agg0 + (size_t)N*3;        // 7*256
    float* scsh = stats + 7*256;             // 7*256 (layout keep)
    float* lperm = scsh + 7*256;             // E
    int*   cursor = (int*)(lperm + E);       // N
    int*   rowoff = cursor + N;              // N+1
    int*   perm   = rowoff + N + 1;          // E
    int*   dperm  = perm + E;                // E
    int*   eperm  = dperm + E;               // E
    unsigned short* w2t = (unsigned short*)(eperm + E);  // 64*128 bf16
    unsigned short* wT  = w2t + 64*128;                  // 7 * 128*128 bf16

    unsigned short* b0 = (unsigned short*)buf0;
    unsigned short* b1b = (unsigned short*)buf1;
    unsigned short* b2b = (unsigned short*)buf2;

    float* out = (float*)d_out;

    const float* wl = d_w1 + 256*128;   // row 256 of d_w1

    #define STATSK(k) (stats + (k)*256)
    #define WT(m) (wT + (m)*16384)

    const int rowTiles = (N + 63) / 64;
    const int edgeTiles128 = (E + 127) / 128;
    const int eBlocks = (E + 255) / 256;
    const float invN = 1.f / (float)N;
    const float invE = 1.f / (float)E;
    const int nWaves = 2048 * 4;
    const int nspan = (N + nWaves - 1) / nWaves;

    hipMemsetAsync(stats, 0, 7*256 * sizeof(float), stream);
    hipMemsetAsync(cursor, 0, (size_t)N * sizeof(int), stream);

    // CSR build + weight prep
    hist_dst<<<eBlocks, 256, 0, stream>>>(edst, cursor, E);
    scan_deg<<<1, 1024, 0, stream>>>(cursor, rowoff, cursor, N);
    fill_csr<<<eBlocks, 256, 0, stream>>>(esrc, edst, coords, cursor, perm, dperm, eperm, lperm, E);
    prep_w2<<<32, 256, 0, stream>>>(d_w2, w2t);
    prep_wT<<<dim3(64, 7), 256, 0, stream>>>(g0_w2, g0_w3, g1_w1, g1_w2, g1_w3,
                                             d_w1, d_w1 + 128*128, wT);

    // layer 0
    gather_coords<<<(N + 255)/256, 256, 0, stream>>>(coords, rowoff, perm, agg0, N);
    lin0<<<rowTiles, 256, 0, stream>>>(coords, agg0, g0_w1, g0_b1, eps0, b0, STATSK(0), N);
    gemm_mfma<true,true><<<rowTiles, 256, 0, stream>>>(
        b0, WT(0), g0_b2, STATSK(0), g0_g1, g0_be1, invN, b1b, STATSK(1), N);
    gemm_mfma<true,true><<<rowTiles, 256, 0, stream>>>(
        b1b, WT(1), g0_b3, STATSK(1), g0_g2, g0_be2, invN, b2b, STATSK(2), N);

    // layer 1: h1 = (1+eps1)*bnrelu(t3) + gather(bnrelu(t3))
    gather_combine_bn<<<(N + 3)/4, 256, 0, stream>>>(
        b2b, rowoff, perm, STATSK(2), bn0_g, bn0_b, invN, eps1, b0, N);
    gemm_mfma<false,true><<<rowTiles, 256, 0, stream>>>(
        b0, WT(2), g1_b1, nullptr, nullptr, nullptr, 0.f, b1b, STATSK(3), N);
    gemm_mfma<true,true><<<rowTiles, 256, 0, stream>>>(
        b1b, WT(3), g1_b2, STATSK(3), g1_g1, g1_be1, invN, b2b, STATSK(4), N);
    gemm_mfma<true,true><<<rowTiles, 256, 0, stream>>>(
        b2b, WT(4), g1_b3, STATSK(4), g1_g2, g1_be2, invN, b0, STATSK(5), N);

    // decoder: ya/yb (bf16) from b0 with BN(5) folded into staging
    gemm_mfma<true,false><<<rowTiles, 256, 0, stream>>>(
        b0, WT(5), nullptr, STATSK(5), bn1_g, bn1_b, invN, b1b, nullptr, N);
    gemm_mfma<true,false><<<rowTiles, 256, 0, stream>>>(
        b0, WT(6), nullptr, STATSK(5), bn1_g, bn1_b, invN, b2b, nullptr, N);
    csr_stats<<<2048, 256, 0, stream>>>(b1b, b2b, rowoff, perm, lperm, wl, d_b1,
                                        STATSK(6), N, nspan);
    decoder_fused<<<edgeTiles128, 512, 0, stream>>>(b1b, b2b, lperm, perm, dperm, eperm,
                                                    wl, d_b1, STATSK(6), d_g, d_be, invE,
                                                    w2t, d_b2, d_w3, d_b3, out, E);
}